// Round 7
// baseline (373.458 us; speedup 1.0000x reference)
//
#include <hip/hip_runtime.h>
#include <hip/hip_bf16.h>

#define NB 8
#define NN 256
#define NL 32
#define NQ 8192              // NN*NL
#define NH 64
#define SL ((size_t)NQ * NN) // elements per (b,k) T1 slab

typedef __attribute__((ext_vector_type(8))) short short8v;
typedef __attribute__((ext_vector_type(4))) float float4v;

static __device__ __forceinline__ ushort f2bf(float f) {
  __hip_bfloat16 h = __float2bfloat16(f);
  return *reinterpret_cast<const ushort*>(&h);
}
static __device__ __forceinline__ uint packbf(float a, float b) {
  return (uint)f2bf(a) | ((uint)f2bf(b) << 16);
}

// ---------------------------------------------------------------------------
// Gt[k][m][n] = bf16(G[k][n][m])
// ---------------------------------------------------------------------------
__global__ __launch_bounds__(256) void prep_g(const float* __restrict__ G,
                                              ushort* __restrict__ Gt) {
  __shared__ float t[32][33];
  const int k = blockIdx.z, m0 = blockIdx.x * 32, n0 = blockIdx.y * 32;
  const int tid = threadIdx.x;
  const int c = tid & 31, r8 = tid >> 5;
#pragma unroll
  for (int i = 0; i < 4; ++i) {
    int r = r8 + i * 8;
    t[r][c] = G[((size_t)k * NN + n0 + r) * NN + m0 + c];
  }
  __syncthreads();
#pragma unroll
  for (int i = 0; i < 4; ++i) {
    int rm = r8 + i * 8;
    Gt[((size_t)k * NN + m0 + rm) * NN + n0 + c] = f2bf(t[c][rm]);
  }
}

// ---------------------------------------------------------------------------
// WtF2: stage-3 B fragments (16x16x32) in lane order.
// Entry e = (kj*4 + hb)*64 + lane : 8 bf16 = W[kj*32 + (lane>>4)*8 + i][h],
// h = hb*16 + (lane&15).
// ---------------------------------------------------------------------------
__global__ __launch_bounds__(256) void prep_wf2(const float* __restrict__ W,
                                                ushort* __restrict__ WtF) {
  const int tid = threadIdx.x;
  for (int e = tid; e < 9 * 4 * 64; e += 256) {
    const int ln = e & 63, hb = (e >> 6) & 3, kj = e >> 8;
    const int h = hb * 16 + (ln & 15);
    const int l0 = kj * 32 + (ln >> 4) * 8;
    ushort v[8];
#pragma unroll
    for (int i = 0; i < 8; ++i) v[i] = f2bf(W[(size_t)(l0 + i) * NH + h]);
    *(ulong2*)(WtF + (size_t)e * 8) = *(ulong2*)v;
  }
}

// ---------------------------------------------------------------------------
// Xt[b][q'][n] = bf16(X[b][n][q]),  q = c*32+l,  q' = l*256+c
// ---------------------------------------------------------------------------
__global__ __launch_bounds__(256) void prep_x(const float* __restrict__ X,
                                              ushort* __restrict__ Xt) {
  __shared__ float t[32][33];
  const int qt = blockIdx.x;
  const int n0 = blockIdx.y * 32;
  const int b  = blockIdx.z;
  const int tid = threadIdx.x;
  const int c = tid & 31, r8 = tid >> 5;
  const float* Xb = X + (size_t)b * NN * NQ;
  ushort* Xo = Xt + (size_t)b * SL;
  const size_t q0 = (size_t)qt * 32;
#pragma unroll
  for (int i = 0; i < 4; ++i) {
    int r = r8 + i * 8;
    t[r][c] = Xb[(size_t)(n0 + r) * NQ + q0 + c];
  }
  __syncthreads();
#pragma unroll
  for (int i = 0; i < 4; ++i) {
    int l = r8 + i * 8;
    Xo[((size_t)l * NN + qt) * NN + n0 + c] = f2bf(t[c][l]);
  }
}

// ---------------------------------------------------------------------------
// Stage 1 GEMM: C[M][N] = A[M][K] * Bt[N][K]^T  (bf16, fp32 acc, 128x128 tile)
// ---------------------------------------------------------------------------
__global__ __launch_bounds__(256) void gemm_bt(
    const ushort* __restrict__ A, const ushort* __restrict__ Bt,
    ushort* __restrict__ C, int N, int K,
    size_t aMs, size_t bDs, size_t cs) {
  __shared__ short As[128][40];
  __shared__ short Bs[128][40];
  const int z = blockIdx.z;
  A  += (size_t)(z % 3) * aMs;
  Bt += (size_t)(z / 3) * bDs;
  C  += (size_t)z * cs;
  const int n0 = blockIdx.x * 128;
  const int m0 = blockIdx.y * 128;
  const int tid = threadIdx.x;
  const int lane = tid & 63;
  const int w = tid >> 6;
  const int wr = (w >> 1) * 64, wc = (w & 1) * 64;
  const int sr = tid >> 1, sc = (tid & 1) * 16;
  const int fr = lane & 15, fg = (lane >> 4) * 8;

  float4v acc[4][4] = {};

  const ushort* ap = A + (size_t)(m0 + sr) * K + sc;
  const ushort* bp = Bt + (size_t)(n0 + sr) * K + sc;

  for (int kk = 0; kk < K; kk += 32) {
    *(float4*)&As[sr][sc]     = *(const float4*)(ap + kk);
    *(float4*)&As[sr][sc + 8] = *(const float4*)(ap + kk + 8);
    *(float4*)&Bs[sr][sc]     = *(const float4*)(bp + kk);
    *(float4*)&Bs[sr][sc + 8] = *(const float4*)(bp + kk + 8);
    __syncthreads();
    short8v af[4], bf[4];
#pragma unroll
    for (int i = 0; i < 4; ++i)
      af[i] = *(const short8v*)&As[wr + i * 16 + fr][fg];
#pragma unroll
    for (int j = 0; j < 4; ++j)
      bf[j] = *(const short8v*)&Bs[wc + j * 16 + fr][fg];
#pragma unroll
    for (int i = 0; i < 4; ++i)
#pragma unroll
      for (int j = 0; j < 4; ++j)
        acc[i][j] = __builtin_amdgcn_mfma_f32_16x16x32_bf16(af[i], bf[j],
                                                            acc[i][j], 0, 0, 0);
    __syncthreads();
  }

  const int rbase = (lane >> 4) * 4;
#pragma unroll
  for (int i = 0; i < 4; ++i) {
    const int row = m0 + wr + i * 16 + rbase;
#pragma unroll
    for (int j = 0; j < 4; ++j) {
      const int col = n0 + wc + j * 16 + fr;
      ushort* cp = C + (size_t)row * N + col;
#pragma unroll
      for (int r = 0; r < 4; ++r)
        cp[(size_t)r * N] = f2bf(acc[i][j][r]);
    }
  }
}

// ---------------------------------------------------------------------------
// Fused stage 2+3 v4: NO main-loop LDS, NO main-loop barriers.
// Block tile 128 ml x 128 d; 4 waves (2 wm x 2 wdh), wave tile 64x64 of
// 16x16x32 frags loaded DIRECTLY from global (16 rows x 64B = full sectors,
// L2-hot under XCD swizzle). C2 -> stage3 A-operand via 4-lane shfl
// butterfly; W pre-packed as B-fragments. Epilogue via 34.8 KB LDS,
// fully coalesced fp32 stores.
// ---------------------------------------------------------------------------
__global__ __launch_bounds__(256, 2) void fused_s23(
    const ushort* __restrict__ T1, const ushort* __restrict__ Gt,
    const ushort* __restrict__ WtF, const float* __restrict__ bias,
    float* __restrict__ out) {
  __shared__ float EP[128][68];

  const int tid = threadIdx.x;
  const int f = blockIdx.x;                  // 1024 blocks
  const int lid = (f & 7) * 128 + (f >> 3);  // XCD-contiguous logical id
  const int dblk = lid & 1;
  const int mp   = (lid >> 1) & 63;
  const int b    = lid >> 7;

  const int lane = tid & 63;
  const int w   = tid >> 6;
  const int wm  = w >> 1;          // wave ml-half (2 m-values)
  const int wdh = w & 1;           // wave d-half
  const int fr  = lane & 15;
  const int rg  = lane >> 4;       // 0..3
  const int fg  = rg * 8;
  const int d0  = dblk * 128;

  const ushort* t1b = T1 + ((size_t)b * 3) * SL + (size_t)mp * 128 * 256;

  float4v acc3[2][4][4] = {};      // [m_local][ds][hb]

  // shuffle source lanes for the C2 -> A-frag transpose (lane-invariant)
  const int s0 = fr + 32 * (rg & 1);
  const int s1 = s0 + 16;
  const bool hi = (rg >= 2);

  for (int kj = 0; kj < 9; ++kj) {
    const int k = kj / 3;
    const int j = kj - 3 * k;
    const ushort* t1k = t1b + (size_t)k * SL + ((size_t)(wm * 64 + fr)) * 256 + fg;
    const ushort* gtj = Gt + (size_t)j * NN * NN +
                        ((size_t)(d0 + wdh * 64 + fr)) * 256 + fg;

    // stage3 B-frags (W), one coalesced 1KB wave load each, L2-hot
    short8v Bw[4];
#pragma unroll
    for (int hb = 0; hb < 4; ++hb)
      Bw[hb] = *(const short8v*)(WtF + ((size_t)((kj * 4 + hb) * 64 + lane)) * 8);

    // ---- stage 2: 8 K-steps, 4x4 frags, direct global loads
    float4v acc2[4][4] = {};
#pragma unroll
    for (int kk8 = 0; kk8 < 8; ++kk8) {
      const int kk = kk8 * 32;
      short8v af[4], bf[4];
#pragma unroll
      for (int i = 0; i < 4; ++i)
        af[i] = *(const short8v*)(t1k + (size_t)i * 16 * 256 + kk);
#pragma unroll
      for (int jj = 0; jj < 4; ++jj)
        bf[jj] = *(const short8v*)(gtj + (size_t)jj * 16 * 256 + kk);
#pragma unroll
      for (int i = 0; i < 4; ++i)
#pragma unroll
        for (int jj = 0; jj < 4; ++jj)
          acc2[i][jj] = __builtin_amdgcn_mfma_f32_16x16x32_bf16(
              af[i], bf[jj], acc2[i][jj], 0, 0, 0);
    }

    // ---- transpose C2 -> stage3 A-frags (shfl butterfly) + stage3 MFMA
#pragma unroll
    for (int ml = 0; ml < 2; ++ml) {
#pragma unroll
      for (int ds = 0; ds < 4; ++ds) {
        const float4v F0 = acc2[ml * 2 + 0][ds];   // l16 = rg*4..rg*4+3 (lb 0)
        const float4v F1 = acc2[ml * 2 + 1][ds];   // lb 1
        const uint f0u0 = packbf(F0[0], F0[1]);
        const uint f0u1 = packbf(F0[2], F0[3]);
        const uint f1u0 = packbf(F1[0], F1[1]);
        const uint f1u1 = packbf(F1[2], F1[3]);
        const uint a00 = (uint)__shfl((int)f0u0, s0);
        const uint a01 = (uint)__shfl((int)f0u1, s0);
        const uint a02 = (uint)__shfl((int)f0u0, s1);
        const uint a03 = (uint)__shfl((int)f0u1, s1);
        const uint a10 = (uint)__shfl((int)f1u0, s0);
        const uint a11 = (uint)__shfl((int)f1u1, s0);
        const uint a12 = (uint)__shfl((int)f1u0, s1);
        const uint a13 = (uint)__shfl((int)f1u1, s1);
        uint4 u;
        u.x = hi ? a10 : a00;
        u.y = hi ? a11 : a01;
        u.z = hi ? a12 : a02;
        u.w = hi ? a13 : a03;
        const short8v Am = *(const short8v*)&u;    // A[d16][l = 8g+e]
#pragma unroll
        for (int hb = 0; hb < 4; ++hb)
          acc3[ml][ds][hb] = __builtin_amdgcn_mfma_f32_16x16x32_bf16(
              Am, Bw[hb], acc3[ml][ds][hb], 0, 0, 0);
      }
    }
  }

  // ---- epilogue: 4 passes (one per m); stage [d 128][h 64] fp32 in LDS,
  //      then fully-coalesced stores with bias+ReLU.
#pragma unroll
  for (int mm = 0; mm < 4; ++mm) {
    if (wm == (mm >> 1)) {
      const int ml = mm & 1;
#pragma unroll
      for (int ds = 0; ds < 4; ++ds)
#pragma unroll
        for (int hb = 0; hb < 4; ++hb)
#pragma unroll
          for (int r = 0; r < 4; ++r)
            EP[wdh * 64 + ds * 16 + rg * 4 + r][hb * 16 + fr] =
                acc3[ml][ds][hb][r];
    }
    __syncthreads();
    const int m = mp * 4 + mm;
    float* ob = out + (((size_t)b * NN + m) * NN + d0) * NH;
#pragma unroll
    for (int ii = 0; ii < 8; ++ii) {
      const int fi = tid + ii * 256;     // 0..2047 float4
      const int d  = fi >> 4;
      const int hg = fi & 15;
      float4 v = *(const float4*)&EP[d][hg * 4];
      const float4 bb = *(const float4*)(bias + hg * 4);
      v.x = fmaxf(v.x + bb.x, 0.f);
      v.y = fmaxf(v.y + bb.y, 0.f);
      v.z = fmaxf(v.z + bb.z, 0.f);
      v.w = fmaxf(v.w + bb.w, 0.f);
      *(float4*)(ob + (size_t)d * NH + hg * 4) = v;
    }
    __syncthreads();
  }
}

extern "C" void kernel_launch(void* const* d_in, const int* in_sizes, int n_in,
                              void* d_out, int out_size, void* d_ws, size_t ws_size,
                              hipStream_t stream) {
  (void)in_sizes; (void)n_in; (void)out_size; (void)ws_size;
  const float* X    = (const float*)d_in[0];
  const float* G    = (const float*)d_in[1];
  const float* W    = (const float*)d_in[2];
  const float* bias = (const float*)d_in[3];
  float* out = (float*)d_out;

  char* p = (char*)d_ws;
  ushort* Gt  = (ushort*)p;  p += (size_t)3 * NN * NN * 2;  // 384 KB
  ushort* WtF = (ushort*)p;  p += (size_t)64 * 1024;        // 36.9 KB (padded)
  ushort* Xt  = (ushort*)p;  p += (size_t)NB * SL * 2;      // 33.5 MB
  ushort* T1  = (ushort*)p;                                 // 100.7 MB

  prep_g<<<dim3(8, 8, 3), 256, 0, stream>>>(G, Gt);
  prep_wf2<<<dim3(1), 256, 0, stream>>>(W, WtF);
  prep_x<<<dim3(256, 8, NB), 256, 0, stream>>>(X, Xt);

  // Stage 1 for all (b,k): z = b*3+k ; A = Gt[k], Bt = Xt[b], C = T1[z]
  gemm_bt<<<dim3(NQ / 128, NN / 128, 24), 256, 0, stream>>>(
      Gt, Xt, T1, NQ, NN, (size_t)NN * NN, SL, SL);

  // Fused stage 2+3 (1024 logical blocks, XCD-swizzled)
  fused_s23<<<dim3(1024), 256, 0, stream>>>(T1, Gt, WtF, bias, out);
}

// Round 8
// 209.163 us; speedup vs baseline: 1.7855x; 1.7855x over previous
//
#include <hip/hip_runtime.h>
#include <hip/hip_bf16.h>

#define NB 8
#define NN 256
#define NL 32
#define NQ 8192              // NN*NL
#define NH 64
#define SL ((size_t)NQ * NN) // elements per (b,k) T1 slab

typedef __attribute__((ext_vector_type(8))) short short8v;
typedef __attribute__((ext_vector_type(4))) float float4v;
typedef __attribute__((ext_vector_type(16))) float float16v;

static __device__ __forceinline__ ushort f2bf(float f) {
  __hip_bfloat16 h = __float2bfloat16(f);
  return *reinterpret_cast<const ushort*>(&h);
}
static __device__ __forceinline__ uint packbf(float a, float b) {
  return (uint)f2bf(a) | ((uint)f2bf(b) << 16);
}
static __device__ __forceinline__ void gld_lds16(const void* g, void* l) {
  __builtin_amdgcn_global_load_lds(
      (const __attribute__((address_space(1))) unsigned int*)g,
      (__attribute__((address_space(3))) unsigned int*)l, 16, 0, 0);
}

// ---------------------------------------------------------------------------
// Gt[k][m][n] = bf16(G[k][n][m])
// ---------------------------------------------------------------------------
__global__ __launch_bounds__(256) void prep_g(const float* __restrict__ G,
                                              ushort* __restrict__ Gt) {
  __shared__ float t[32][33];
  const int k = blockIdx.z, m0 = blockIdx.x * 32, n0 = blockIdx.y * 32;
  const int tid = threadIdx.x;
  const int c = tid & 31, r8 = tid >> 5;
#pragma unroll
  for (int i = 0; i < 4; ++i) {
    int r = r8 + i * 8;
    t[r][c] = G[((size_t)k * NN + n0 + r) * NN + m0 + c];
  }
  __syncthreads();
#pragma unroll
  for (int i = 0; i < 4; ++i) {
    int rm = r8 + i * 8;
    Gt[((size_t)k * NN + m0 + rm) * NN + n0 + c] = f2bf(t[c][rm]);
  }
}

// ---------------------------------------------------------------------------
// WtF: stage-3 A fragments in lane order. Entry e = ((kj*2+kp)*2+hb)*64+lane,
// 16B granule = 8 bf16 of W rows (kj*32+kp*16+(lane>>5)*8 + 0..7), col h.
// ---------------------------------------------------------------------------
__global__ __launch_bounds__(256) void prep_wf(const float* __restrict__ W,
                                               ushort* __restrict__ WtF) {
  const int tid = threadIdx.x;
  for (int e = tid; e < 9 * 2 * 2 * 64; e += 256) {
    const int ln = e & 63, hb = (e >> 6) & 1, kp = (e >> 7) & 1, kj = e >> 8;
    const int h = hb * 32 + (ln & 31);
    const int c0 = kj * 32 + kp * 16 + (ln >> 5) * 8;
    ushort v[8];
#pragma unroll
    for (int i = 0; i < 8; ++i) v[i] = f2bf(W[(size_t)(c0 + i) * NH + h]);
    *(ulong2*)(WtF + (size_t)e * 8) = *(ulong2*)v;
  }
}

// ---------------------------------------------------------------------------
// Xt[b][q'][n] = bf16(X[b][n][q]),  q = c*32+l,  q' = l*256+c
// ---------------------------------------------------------------------------
__global__ __launch_bounds__(256) void prep_x(const float* __restrict__ X,
                                              ushort* __restrict__ Xt) {
  __shared__ float t[32][33];
  const int qt = blockIdx.x;
  const int n0 = blockIdx.y * 32;
  const int b  = blockIdx.z;
  const int tid = threadIdx.x;
  const int c = tid & 31, r8 = tid >> 5;
  const float* Xb = X + (size_t)b * NN * NQ;
  ushort* Xo = Xt + (size_t)b * SL;
  const size_t q0 = (size_t)qt * 32;
#pragma unroll
  for (int i = 0; i < 4; ++i) {
    int r = r8 + i * 8;
    t[r][c] = Xb[(size_t)(n0 + r) * NQ + q0 + c];
  }
  __syncthreads();
#pragma unroll
  for (int i = 0; i < 4; ++i) {
    int l = r8 + i * 8;
    Xo[((size_t)l * NN + qt) * NN + n0 + c] = f2bf(t[c][l]);
  }
}

// ---------------------------------------------------------------------------
// Stage 1 GEMM: C[M][N] = A[M][K] * Bt[N][K]^T  (bf16, fp32 acc, 128x128 tile)
// ---------------------------------------------------------------------------
__global__ __launch_bounds__(256) void gemm_bt(
    const ushort* __restrict__ A, const ushort* __restrict__ Bt,
    ushort* __restrict__ C, int N, int K,
    size_t aMs, size_t bDs, size_t cs) {
  __shared__ short As[128][40];
  __shared__ short Bs[128][40];
  const int z = blockIdx.z;
  A  += (size_t)(z % 3) * aMs;
  Bt += (size_t)(z / 3) * bDs;
  C  += (size_t)z * cs;
  const int n0 = blockIdx.x * 128;
  const int m0 = blockIdx.y * 128;
  const int tid = threadIdx.x;
  const int lane = tid & 63;
  const int w = tid >> 6;
  const int wr = (w >> 1) * 64, wc = (w & 1) * 64;
  const int sr = tid >> 1, sc = (tid & 1) * 16;
  const int fr = lane & 15, fg = (lane >> 4) * 8;

  float4v acc[4][4] = {};

  const ushort* ap = A + (size_t)(m0 + sr) * K + sc;
  const ushort* bp = Bt + (size_t)(n0 + sr) * K + sc;

  for (int kk = 0; kk < K; kk += 32) {
    *(float4*)&As[sr][sc]     = *(const float4*)(ap + kk);
    *(float4*)&As[sr][sc + 8] = *(const float4*)(ap + kk + 8);
    *(float4*)&Bs[sr][sc]     = *(const float4*)(bp + kk);
    *(float4*)&Bs[sr][sc + 8] = *(const float4*)(bp + kk + 8);
    __syncthreads();
    short8v af[4], bf[4];
#pragma unroll
    for (int i = 0; i < 4; ++i)
      af[i] = *(const short8v*)&As[wr + i * 16 + fr][fg];
#pragma unroll
    for (int j = 0; j < 4; ++j)
      bf[j] = *(const short8v*)&Bs[wc + j * 16 + fr][fg];
#pragma unroll
    for (int i = 0; i < 4; ++i)
#pragma unroll
      for (int j = 0; j < 4; ++j)
        acc[i][j] = __builtin_amdgcn_mfma_f32_16x16x32_bf16(af[i], bf[j],
                                                            acc[i][j], 0, 0, 0);
    __syncthreads();
  }

  const int rbase = (lane >> 4) * 4;
#pragma unroll
  for (int i = 0; i < 4; ++i) {
    const int row = m0 + wr + i * 16 + rbase;
#pragma unroll
    for (int j = 0; j < 4; ++j) {
      const int col = n0 + wc + j * 16 + fr;
      ushort* cp = C + (size_t)row * N + col;
#pragma unroll
      for (int r = 0; r < 4; ++r)
        cp[(size_t)r * N] = f2bf(acc[i][j][r]);
    }
  }
}

// ---------------------------------------------------------------------------
// Fused stage 2+3 v5: round-6 pipeline + 256B-pitch LDS quarters (no bank
// conflicts). Block tile 128 ml x 128 d, 4 waves (2x2), wave tile 64x64.
// 36 tiles = 9 (k,j) x 4 K-quarters (64 c). Each 16 KB quarter packs TWO
// 64-col data rows per 256B LDS row: data (dr,g) at LDS row R=dr>>1,
// slot ((dr&1)*8+g)^(R&15)  -> identical bank pattern to the round-5 layout
// that measured ZERO conflicts. Ping-pong 32 KB buffer pairs; per iter
// {sync; DMA(t+1 -> buf^1); compute(t <- buf)}. Stage3 after each 4th
// quarter (in-reg transpose + WtF MFMA). Epilogue via swizzled LDS.
// ---------------------------------------------------------------------------
__global__ __launch_bounds__(256, 2) void fused_s23(
    const ushort* __restrict__ T1, const ushort* __restrict__ Gt,
    const ushort* __restrict__ WtF, const float* __restrict__ bias,
    float* __restrict__ out) {
  __shared__ ulong2 LDSQ[4096];              // 64 KB
  char* base = (char*)LDSQ;

  const int tid = threadIdx.x;
  const int f = blockIdx.x;                  // 1024 blocks
  const int lid = (f & 7) * 128 + (f >> 3);  // XCD-contiguous logical id
  const int dblk = lid & 1;
  const int mp   = (lid >> 1) & 63;
  const int b    = lid >> 7;

  const int lane = tid & 63;
  const int w  = tid >> 6;
  const int l5 = lane & 31;
  const int h5 = lane >> 5;
  const int wml = (w >> 1) * 64;             // wave ml-base in tile
  const int wd  = (w & 1) * 64;              // wave d-base in tile
  const int d0  = dblk * 128;

  const ushort* t1b  = T1 + ((size_t)b * 3) * SL + (size_t)mp * 128 * 256;
  const ushort* gtb0 = Gt + (size_t)d0 * NN;

  // DMA-stage tile t (= kj*4 + quarter) into buffer at byte offset qb.
  // Linear LDS dest; source address carries the inverse swizzle.
  auto stage = [&](int t, int qb) {
    const int kj = t >> 2, q = t & 3;
    const int k = (kj >= 6) ? 2 : (kj >= 3 ? 1 : 0);
    const int j = kj - k * 3;
    const ushort* t1k = t1b + (size_t)k * SL + q * 64;
    const ushort* gtj = gtb0 + (size_t)j * NN * NN + q * 64;
    char* d1 = base + qb + ((tid & 192) << 4);
    char* d2 = d1 + 16384;
#pragma unroll
    for (int i = 0; i < 4; ++i) {
      const int gl = i * 256 + tid;          // linear granule 0..1023
      const int R  = gl >> 4;
      const int sd = (gl & 15) ^ (R & 15);   // data slot at this position
      const int dr = 2 * R + (sd >> 3);      // data row 0..127
      const int g  = sd & 7;                 // 16B granule within 64 cols
      gld_lds16(t1k + (size_t)dr * 256 + g * 8, d1 + (i << 12));
      gld_lds16(gtj + (size_t)dr * 256 + g * 8, d2 + (i << 12));
    }
  };
  // Swizzled b128 read: data (row, gq) -> LDS row row>>1, 16-slot XOR.
  auto ldv = [&](int qb, int toff, int row, int gq) -> short8v {
    const int R = row >> 1;
    const int s = (((row & 1) << 3) + gq) ^ (R & 15);
    return *(const short8v*)(base + qb + toff + (((R << 4) + s) << 4));
  };

  float16v acc3[2][2][2] = {};   // [msub][dsub][hb]
  float16v acc2[2][2] = {};      // [msub][dsub]

  stage(0, 0);                   // prologue

  for (int t = 0; t < 36; ++t) {
    const int qb = (t & 1) << 15;
    __syncthreads();             // tile t drained & visible; buf^1 reads done
    if (t + 1 < 36) stage(t + 1, qb ^ 32768);

    // ---- compute quarter: 4 K-steps x 4 MFMA (shared af/bf)
#pragma unroll
    for (int ks = 0; ks < 4; ++ks) {
      const int gq = 2 * ks + h5;
      short8v af0 = ldv(qb, 0,     wml + l5,      gq);
      short8v af1 = ldv(qb, 0,     wml + 32 + l5, gq);
      short8v bf0 = ldv(qb, 16384, wd + l5,       gq);
      short8v bf1 = ldv(qb, 16384, wd + 32 + l5,  gq);
      acc2[0][0] = __builtin_amdgcn_mfma_f32_32x32x16_bf16(af0, bf0, acc2[0][0], 0, 0, 0);
      acc2[0][1] = __builtin_amdgcn_mfma_f32_32x32x16_bf16(af0, bf1, acc2[0][1], 0, 0, 0);
      acc2[1][0] = __builtin_amdgcn_mfma_f32_32x32x16_bf16(af1, bf0, acc2[1][0], 0, 0, 0);
      acc2[1][1] = __builtin_amdgcn_mfma_f32_32x32x16_bf16(af1, bf1, acc2[1][1], 0, 0, 0);
    }

    if ((t & 3) == 3) {
      const int kj = t >> 2;
      // ---- stage3 A-frags (coalesced 1KB wave loads from L2-hot WtF)
      short8v Af[2][2];          // [kp][hb]
#pragma unroll
      for (int kp = 0; kp < 2; ++kp)
#pragma unroll
        for (int hb = 0; hb < 2; ++hb)
          Af[kp][hb] = *(const short8v*)(WtF +
              ((size_t)(((kj * 2 + kp) * 2 + hb) * 64 + lane)) * 8);

      // ---- per C2 tile: in-register transpose -> stage3 B -> 4 MFMA
#pragma unroll
      for (int ms = 0; ms < 2; ++ms) {
#pragma unroll
        for (int ds = 0; ds < 2; ++ds) {
          uint P[8], Xc[8];
#pragma unroll
          for (int q = 0; q < 8; ++q)
            P[q] = packbf(acc2[ms][ds][2 * q], acc2[ms][ds][2 * q + 1]);
#pragma unroll
          for (int q = 0; q < 8; ++q) Xc[q] = (uint)__shfl_xor((int)P[q], 32);
          short8v Bf[2];
#pragma unroll
          for (int kp = 0; kp < 2; ++kp) {
            uint4 u;
            if (h5 == 0) {
              u.x = P[4 * kp];      u.y = P[4 * kp + 1];
              u.z = Xc[4 * kp];     u.w = Xc[4 * kp + 1];
            } else {
              u.x = Xc[4 * kp + 2]; u.y = Xc[4 * kp + 3];
              u.z = P[4 * kp + 2];  u.w = P[4 * kp + 3];
            }
            Bf[kp] = *(short8v*)&u;
          }
#pragma unroll
          for (int hb = 0; hb < 2; ++hb) {
#pragma unroll
            for (int kp = 0; kp < 2; ++kp)
              acc3[ms][ds][hb] = __builtin_amdgcn_mfma_f32_32x32x16_bf16(
                  Af[kp][hb], Bf[kp], acc3[ms][ds][hb], 0, 0, 0);
          }
          // zero acc2 for next (k,j)
#pragma unroll
          for (int q = 0; q < 16; ++q) acc2[ms][ds][q] = 0.f;
        }
      }
    }
  }

  // ---- epilogue: 2 passes of 2 m each; stage fp32 in swizzled LDS, then
  //      fully-coalesced stores with bias+ReLU.
  float4* EP = (float4*)base;    // [ml 2][d 128][hgran 16] float4 = 64 KB
#pragma unroll
  for (int mlp = 0; mlp < 2; ++mlp) {
    __syncthreads();             // LDS free / prior pass consumed
    if ((w >> 1) == mlp) {
#pragma unroll
      for (int ms = 0; ms < 2; ++ms) {
#pragma unroll
        for (int ds = 0; ds < 2; ++ds) {
          const int d = wd + ds * 32 + l5;
#pragma unroll
          for (int hb = 0; hb < 2; ++hb) {
#pragma unroll
            for (int s = 0; s < 4; ++s) {
              const int hg = 2 * s + h5 + 8 * hb;   // float4 granule of h
              float4 v;
              v.x = acc3[ms][ds][hb][4 * s + 0];
              v.y = acc3[ms][ds][hb][4 * s + 1];
              v.z = acc3[ms][ds][hb][4 * s + 2];
              v.w = acc3[ms][ds][hb][4 * s + 3];
              EP[(ms * 128 + d) * 16 + (hg ^ (d & 15))] = v;
            }
          }
        }
      }
    }
    __syncthreads();
    // coalesced store of 2 m rows (2 x 32 KB)
#pragma unroll
    for (int ii = 0; ii < 16; ++ii) {
      const int fi = tid + ii * 256;         // 0..4095 float4
      const int ml = fi >> 11;
      const int d  = (fi >> 4) & 127;
      const int hg = fi & 15;
      float4 v = EP[(ml * 128 + d) * 16 + (hg ^ (d & 15))];
      const float4 bb = *(const float4*)(bias + hg * 4);
      v.x = fmaxf(v.x + bb.x, 0.f);
      v.y = fmaxf(v.y + bb.y, 0.f);
      v.z = fmaxf(v.z + bb.z, 0.f);
      v.w = fmaxf(v.w + bb.w, 0.f);
      const int m = mp * 4 + mlp * 2 + ml;
      float* ob = out + (((size_t)b * NN + m) * NN + d0 + d) * NH;
      *(float4*)(ob + hg * 4) = v;
    }
  }
}

extern "C" void kernel_launch(void* const* d_in, const int* in_sizes, int n_in,
                              void* d_out, int out_size, void* d_ws, size_t ws_size,
                              hipStream_t stream) {
  (void)in_sizes; (void)n_in; (void)out_size; (void)ws_size;
  const float* X    = (const float*)d_in[0];
  const float* G    = (const float*)d_in[1];
  const float* W    = (const float*)d_in[2];
  const float* bias = (const float*)d_in[3];
  float* out = (float*)d_out;

  char* p = (char*)d_ws;
  ushort* Gt  = (ushort*)p;  p += (size_t)3 * NN * NN * 2;  // 384 KB
  ushort* WtF = (ushort*)p;  p += (size_t)64 * 1024;        // 36.9 KB (padded)
  ushort* Xt  = (ushort*)p;  p += (size_t)NB * SL * 2;      // 33.5 MB
  ushort* T1  = (ushort*)p;                                 // 100.7 MB

  prep_g<<<dim3(8, 8, 3), 256, 0, stream>>>(G, Gt);
  prep_wf<<<dim3(1), 256, 0, stream>>>(W, WtF);
  prep_x<<<dim3(256, 8, NB), 256, 0, stream>>>(X, Xt);

  // Stage 1 for all (b,k): z = b*3+k ; A = Gt[k], Bt = Xt[b], C = T1[z]
  gemm_bt<<<dim3(NQ / 128, NN / 128, 24), 256, 0, stream>>>(
      Gt, Xt, T1, NQ, NN, (size_t)NN * NN, SL, SL);

  // Fused stage 2+3 (1024 logical blocks, XCD-swizzled)
  fused_s23<<<dim3(1024), 256, 0, stream>>>(T1, Gt, WtF, bias, out);
}